// Round 10
// baseline (1160.210 us; speedup 1.0000x reference)
//
#include <hip/hip_runtime.h>
#include <hip/hip_bf16.h>

// Problem constants (match reference)
#define NODES 100000
#define EDGES 1600000
#define FEAT  128
#define HID   256
#define CLS   64
#define KPROP 10
#define ALPHA_C 0.1f
#define BETA_C  0.5f
#define BN_EPS  1e-5f

typedef __attribute__((ext_vector_type(8))) short short8;
typedef __attribute__((ext_vector_type(4))) float f32x4;

static __device__ __forceinline__ unsigned short f2b(float f) {
    __hip_bfloat16 h = __float2bfloat16(f);
    return *(unsigned short*)&h;
}
static __device__ __forceinline__ float b2f(unsigned short u) {
    __hip_bfloat16 h;
    *(unsigned short*)&h = u;
    return __bfloat162float(h);
}
static __device__ __forceinline__ float asf(unsigned int u) {
    union { unsigned int u; float f; } c; c.u = u; return c.f;
}

// ---------------------------------------------------------------------------
// Pack W [K,N] fp32 -> Wt [N,K] bf16 (transposed, for B-fragment loads)
// ---------------------------------------------------------------------------
__global__ void packwt_k(const float* __restrict__ W, unsigned short* __restrict__ Wt,
                         int K, int N)
{
    int i = blockIdx.x * 256 + threadIdx.x;
    if (i < K * N) {
        int k = i / N, n = i - k * N;
        Wt[(size_t)n * K + k] = f2b(W[i]);
    }
}

// x fp32 [N][128] -> xb bf16 (8 elems/thread)
__global__ void xcvt_k(const float* __restrict__ x, unsigned short* __restrict__ xb)
{
    int i = blockIdx.x * 256 + threadIdx.x;
    if (i < NODES * FEAT / 8) {
        float4 a = ((const float4*)x)[2 * i];
        float4 b = ((const float4*)x)[2 * i + 1];
        short8 o;
        o[0] = (short)f2b(a.x); o[1] = (short)f2b(a.y);
        o[2] = (short)f2b(a.z); o[3] = (short)f2b(a.w);
        o[4] = (short)f2b(b.x); o[5] = (short)f2b(b.y);
        o[6] = (short)f2b(b.z); o[7] = (short)f2b(b.w);
        ((short8*)xb)[i] = o;
    }
}

// ---------------------------------------------------------------------------
// Layer-1 GEMM (r11 structure + r13 unconditional loads; validated out of
// top-5). Col-split: block = 4 waves x 64 cols -> all 256 cols; B = 64 KB
// LDS; 32-row chunks, chunk-strided; bf16 x read ONCE.
// ---------------------------------------------------------------------------
__global__ __launch_bounds__(256, 2)
void gemm1_k(const unsigned short* __restrict__ xb, const unsigned short* __restrict__ Wt,
             const float* __restrict__ bias, unsigned short* __restrict__ h1,
             float* __restrict__ gsum, float* __restrict__ gsq,
             int M, int nchunks, int nblk)
{
    __shared__ unsigned short Blds[256 * FEAT];   // 64 KB
    const int lane = threadIdx.x & 63;
    const int wv   = threadIdx.x >> 6;
    const int quad = lane >> 4;
    const int l16  = lane & 15;
    const int colbase = wv * 64;

    // stage B: 256 cols x 128 K, swizzled
    #pragma unroll
    for (int i0 = 0; i0 < 4096; i0 += 256) {
        int i  = i0 + threadIdx.x;
        int c  = i >> 4;
        int k8 = i & 15;
        short8 v = *(const short8*)(Wt + (size_t)c * FEAT + k8 * 8);
        int byte = c * 256 + ((k8 * 16) ^ ((c & 7) << 4));
        *(short8*)((char*)Blds + byte) = v;
    }
    __syncthreads();

    float bcol[4];
    #pragma unroll
    for (int ct = 0; ct < 4; ++ct) bcol[ct] = bias[colbase + ct * 16 + l16];
    float ps[4] = {0.f, 0.f, 0.f, 0.f};
    float pq[4] = {0.f, 0.f, 0.f, 0.f};

    short8 ah0[2][4], ah1[2][4];

#define LOAD1(AH, CHK)                                                         \
    if ((CHK) < nchunks) {                                                     \
        const int rb_ = (CHK) * 32;                                            \
        _Pragma("unroll")                                                      \
        for (int rt = 0; rt < 2; ++rt) {                                       \
            const int row_ = rb_ + rt * 16 + l16;                              \
            const unsigned short* ap_ = xb + (size_t)row_ * FEAT + quad * 8;   \
            _Pragma("unroll")                                                  \
            for (int ks = 0; ks < 4; ++ks)                                     \
                AH[rt][ks] = *(const short8*)(ap_ + ks * 32);                  \
        }                                                                      \
    }

#define COMP1(AH, CHK)                                                         \
    {                                                                          \
        const int rb_ = (CHK) * 32;                                            \
        f32x4 acc[2][4];                                                       \
        _Pragma("unroll")                                                      \
        for (int i = 0; i < 2; ++i)                                            \
            _Pragma("unroll")                                                  \
            for (int j = 0; j < 4; ++j)                                        \
                acc[i][j] = (f32x4){0.f, 0.f, 0.f, 0.f};                       \
        _Pragma("unroll")                                                      \
        for (int ks = 0; ks < 4; ++ks) {                                       \
            _Pragma("unroll")                                                  \
            for (int ct = 0; ct < 4; ++ct) {                                   \
                const int col_ = colbase + ct * 16 + l16;                      \
                const int boff = col_ * 256                                    \
                               + ((ks * 64 + quad * 16) ^ ((col_ & 7) << 4));  \
                short8 bf = *(const short8*)((const char*)Blds + boff);        \
                acc[0][ct] = __builtin_amdgcn_mfma_f32_16x16x32_bf16(AH[0][ks], bf, acc[0][ct], 0, 0, 0); \
                acc[1][ct] = __builtin_amdgcn_mfma_f32_16x16x32_bf16(AH[1][ks], bf, acc[1][ct], 0, 0, 0); \
            }                                                                  \
        }                                                                      \
        _Pragma("unroll")                                                      \
        for (int ct = 0; ct < 4; ++ct) {                                       \
            const int col_ = colbase + ct * 16 + l16;                          \
            _Pragma("unroll")                                                  \
            for (int rt = 0; rt < 2; ++rt) {                                   \
                _Pragma("unroll")                                              \
                for (int r2 = 0; r2 < 4; ++r2) {                               \
                    const int row_ = rb_ + rt * 16 + quad * 4 + r2;            \
                    if (row_ < M) {                                            \
                        float vv = acc[rt][ct][r2] + bcol[ct];                 \
                        ps[ct] += vv; pq[ct] += vv * vv;                       \
                        h1[(size_t)row_ * HID + col_] = f2b(vv);               \
                    }                                                          \
                }                                                              \
            }                                                                  \
        }                                                                      \
    }

    int chunk = blockIdx.x;
    LOAD1(ah0, chunk)
    while (chunk < nchunks) {
        const int cn1 = chunk + nblk;
        LOAD1(ah1, cn1)
        __builtin_amdgcn_sched_barrier(0);
        COMP1(ah0, chunk)
        chunk = cn1;
        if (chunk >= nchunks) break;
        const int cn2 = chunk + nblk;
        LOAD1(ah0, cn2)
        __builtin_amdgcn_sched_barrier(0);
        COMP1(ah1, chunk)
        chunk = cn2;
    }
#undef LOAD1
#undef COMP1

    #pragma unroll
    for (int ct = 0; ct < 4; ++ct) {
        float s = ps[ct];
        s += __shfl_xor(s, 16, 64);
        s += __shfl_xor(s, 32, 64);
        float q = pq[ct];
        q += __shfl_xor(q, 16, 64);
        q += __shfl_xor(q, 32, 64);
        if (lane < 16) {
            atomicAdd(&gsum[colbase + ct * 16 + lane], s);
            atomicAdd(&gsq[colbase + ct * 16 + lane], q);
        }
    }
}

// ---------------------------------------------------------------------------
// GEMM v5 (layers 2-3; r13, kept unchanged this round for clean attribution).
// Unconditional A loads (padded A), COLS=128/NCOLG=2 for layer 2 (FETCH
// halved, confirmed r13), half-chunk pipelining.
// ---------------------------------------------------------------------------
template<bool FUSE, bool STATS, bool OUTF32, int KK, int NCOLG, int COLS>
__global__ __launch_bounds__(256, 2)
void gemm_lds_k(const unsigned short* __restrict__ Ain, const unsigned short* __restrict__ Wt,
                const float* __restrict__ bias,
                const float* __restrict__ scale, const float* __restrict__ shift,
                void* __restrict__ outp,
                float* __restrict__ gsum, float* __restrict__ gsq,
                int M, int N, int nchunks, int nblk)
{
    constexpr int NK8 = KK / 32;
    constexpr int NKH = NK8 / 2;                 // ks per half-chunk
    constexpr int CHROWS = (COLS == 128) ? 64 : 128;
    __shared__ unsigned short Blds[COLS * KK];   // 64 KB (both configs, KK=256)
    __shared__ float Slds[KK];
    __shared__ float Hlds[KK];

    const int lane = threadIdx.x & 63;
    const int wv   = threadIdx.x >> 6;
    const int quad = lane >> 4;
    const int l16  = lane & 15;
    const int colg = (NCOLG > 1) ? (blockIdx.x % NCOLG) : 0;
    const int blk0 = (NCOLG > 1) ? (blockIdx.x / NCOLG) : blockIdx.x;
    const int colpan = colg * COLS;                            // global panel base
    const int lwcol  = (COLS == 128) ? (wv & 1) * 64 : 0;      // wave local col base
    const int rwoff  = (COLS == 128) ? (wv >> 1) * 32 : wv * 32;

    {
        const unsigned short* wp = Wt + (size_t)colpan * KK;
        constexpr int ELEMS = COLS * KK / 8;
        #pragma unroll
        for (int i0 = 0; i0 < ELEMS; i0 += 256) {
            int i  = i0 + threadIdx.x;
            int c  = i / (KK / 8);
            int k8 = i - c * (KK / 8);
            short8 v = *(const short8*)(wp + (size_t)c * KK + k8 * 8);
            int byte = c * (KK * 2) + ((k8 * 16) ^ ((c & 7) << 4));
            *(short8*)((char*)Blds + byte) = v;
        }
        if constexpr (FUSE) {
            for (int i = threadIdx.x; i < KK; i += 256) {
                Slds[i] = scale[i];
                Hlds[i] = shift[i];
            }
        }
    }
    __syncthreads();

    float bcol[4];
    #pragma unroll
    for (int ct = 0; ct < 4; ++ct) bcol[ct] = bias[colpan + lwcol + ct * 16 + l16];

    float ps[4] = {0.f, 0.f, 0.f, 0.f};
    float pq[4] = {0.f, 0.f, 0.f, 0.f};

    short8 hb0[2][NKH], hb1[2][NKH];
    f32x4 acc[2][4];

#define LOADH(B, CHK, H)                                                       \
    if ((CHK) < nchunks) {                                                     \
        const int rb_ = (CHK) * CHROWS + rwoff;                                \
        _Pragma("unroll")                                                      \
        for (int rt = 0; rt < 2; ++rt) {                                       \
            const int row_ = rb_ + rt * 16 + l16;                              \
            const unsigned short* ap_ = Ain + (size_t)row_ * KK                \
                                        + (H) * NKH * 32 + quad * 8;           \
            _Pragma("unroll")                                                  \
            for (int ks = 0; ks < NKH; ++ks)                                   \
                B[rt][ks] = *(const short8*)(ap_ + ks * 32);                   \
        }                                                                      \
    }

#define COMPH(B, H)                                                            \
    {                                                                          \
        _Pragma("unroll")                                                      \
        for (int ks = 0; ks < NKH; ++ks) {                                     \
            const int gks = (H) * NKH + ks;                                    \
            const int k_ = gks * 32 + quad * 8;                                \
            float sc[8], sh[8];                                                \
            if constexpr (FUSE) {                                              \
                float4 s0 = *(const float4*)&Slds[k_];                         \
                float4 s1 = *(const float4*)&Slds[k_ + 4];                     \
                float4 h0 = *(const float4*)&Hlds[k_];                         \
                float4 h1 = *(const float4*)&Hlds[k_ + 4];                     \
                sc[0]=s0.x; sc[1]=s0.y; sc[2]=s0.z; sc[3]=s0.w;                \
                sc[4]=s1.x; sc[5]=s1.y; sc[6]=s1.z; sc[7]=s1.w;                \
                sh[0]=h0.x; sh[1]=h0.y; sh[2]=h0.z; sh[3]=h0.w;                \
                sh[4]=h1.x; sh[5]=h1.y; sh[6]=h1.z; sh[7]=h1.w;                \
            }                                                                  \
            short8 a2[2];                                                      \
            _Pragma("unroll")                                                  \
            for (int rt = 0; rt < 2; ++rt) {                                   \
                if constexpr (FUSE) {                                          \
                    float v[8];                                                \
                    _Pragma("unroll")                                          \
                    for (int j = 0; j < 8; ++j)                                \
                        v[j] = b2f((unsigned short)B[rt][ks][j]);              \
                    _Pragma("unroll")                                          \
                    for (int j = 0; j < 8; ++j)                                \
                        v[j] = fmaxf(fmaf(v[j], sc[j], sh[j]), 0.f);           \
                    short8 av;                                                 \
                    _Pragma("unroll")                                          \
                    for (int j = 0; j < 8; ++j) av[j] = (short)f2b(v[j]);      \
                    a2[rt] = av;                                               \
                } else {                                                       \
                    a2[rt] = B[rt][ks];                                        \
                }                                                              \
            }                                                                  \
            _Pragma("unroll")                                                  \
            for (int ct = 0; ct < 4; ++ct) {                                   \
                const int lc_ = lwcol + ct * 16 + l16;                         \
                const int boff = lc_ * (KK * 2)                                \
                               + ((gks * 64 + quad * 16) ^ ((l16 & 7) << 4));  \
                short8 bf = *(const short8*)((const char*)Blds + boff);        \
                acc[0][ct] = __builtin_amdgcn_mfma_f32_16x16x32_bf16(a2[0], bf, acc[0][ct], 0, 0, 0); \
                acc[1][ct] = __builtin_amdgcn_mfma_f32_16x16x32_bf16(a2[1], bf, acc[1][ct], 0, 0, 0); \
            }                                                                  \
        }                                                                      \
    }

    int chunk = blk0;
    LOADH(hb0, chunk, 0)
    while (chunk < nchunks) {
        #pragma unroll
        for (int i = 0; i < 2; ++i)
            #pragma unroll
            for (int j = 0; j < 4; ++j)
                acc[i][j] = (f32x4){0.f, 0.f, 0.f, 0.f};

        LOADH(hb1, chunk, 1)
        __builtin_amdgcn_sched_barrier(0);
        COMPH(hb0, 0)
        const int nxt = chunk + nblk;
        LOADH(hb0, nxt, 0)
        __builtin_amdgcn_sched_barrier(0);
        COMPH(hb1, 1)

        // epilogue: bias, store, stats
        const int rb_ = chunk * CHROWS + rwoff;
        #pragma unroll
        for (int ct = 0; ct < 4; ++ct) {
            const int col_ = colpan + lwcol + ct * 16 + l16;
            #pragma unroll
            for (int rt = 0; rt < 2; ++rt) {
                #pragma unroll
                for (int r2 = 0; r2 < 4; ++r2) {
                    const int row_ = rb_ + rt * 16 + quad * 4 + r2;
                    if (row_ < M) {
                        float vv = acc[rt][ct][r2] + bcol[ct];
                        if constexpr (STATS) { ps[ct] += vv; pq[ct] += vv * vv; }
                        if constexpr (OUTF32) {
                            ((float*)outp)[(size_t)row_ * N + col_] = vv;
                        } else {
                            ((unsigned short*)outp)[(size_t)row_ * N + col_] = f2b(vv);
                        }
                    }
                }
            }
        }
        chunk = nxt;
    }
#undef LOADH
#undef COMPH

    if constexpr (STATS) {
        #pragma unroll
        for (int ct = 0; ct < 4; ++ct) {
            float s = ps[ct];
            s += __shfl_xor(s, 16, 64);
            s += __shfl_xor(s, 32, 64);
            float q = pq[ct];
            q += __shfl_xor(q, 16, 64);
            q += __shfl_xor(q, 32, 64);
            if (lane < 16) {
                atomicAdd(&gsum[colpan + lwcol + ct * 16 + lane], s);
                atomicAdd(&gsq[colpan + lwcol + ct * 16 + lane], q);
            }
        }
    }
}

__global__ void bnfin_k(const float* __restrict__ sum, const float* __restrict__ sq,
                        const float* __restrict__ g, const float* __restrict__ be,
                        float* __restrict__ scale, float* __restrict__ shift)
{
    int c = threadIdx.x;  // 256
    float mu = sum[c] * (1.f / NODES);
    float var = sq[c] * (1.f / NODES) - mu * mu;
    float sc = g[c] * rsqrtf(var + BN_EPS);
    scale[c] = sc;
    shift[c] = be[c] - mu * sc;
}

// ---------------------------------------------------------------------------
// use_x flag: any nonzero in z_sam -> flag=1 (flag pre-zeroed)
// ---------------------------------------------------------------------------
__global__ void flag_k(const float* __restrict__ zs, int* __restrict__ flag)
{
    int i = blockIdx.x * 256 + threadIdx.x;
    bool nz = (i < NODES * CLS) && (zs[i] != 0.f);
    if (__any(nz)) {
        if ((threadIdx.x & 63) == 0) *flag = 1;
    }
}

// z0 = flag ? (1-beta)*z_sam + beta*logits : logits  -> 4-PLANE layout
// plane p = c>>4 (16 cols each): z0[((p*N + row)*16) + (c&15)]
__global__ void blend_k(const float* __restrict__ zs, const float* __restrict__ logits,
                        const int* __restrict__ flag, unsigned short* __restrict__ z0)
{
    int i = blockIdx.x * 256 + threadIdx.x;
    if (i < NODES * CLS) {
        float l = logits[i];
        float v = (*flag) ? ((1.f - BETA_C) * zs[i] + BETA_C * l) : l;
        int row = i >> 6, c = i & 63, p = c >> 4;
        z0[((size_t)p * NODES + row) * 16 + (c & 15)] = f2b(v);
    }
}

// ---------------------------------------------------------------------------
// CSR build (r10 validated): replicated counters; pos/scatter split.
// ---------------------------------------------------------------------------
__global__ void count_k(const int* __restrict__ dst, int* __restrict__ cntx)
{
    int t = blockIdx.x * 256 + threadIdx.x;
    if (t >= EDGES / 4) return;
    int4 d = ((const int4*)dst)[t];
    int* c = cntx + (size_t)(blockIdx.x & 7) * NODES;
    atomicAdd(&c[d.x], 1);
    atomicAdd(&c[d.y], 1);
    atomicAdd(&c[d.z], 1);
    atomicAdd(&c[d.w], 1);
}

__global__ void sumoff_k(int* __restrict__ cntx, int* __restrict__ cnt)
{
    int n = blockIdx.x * 256 + threadIdx.x;
    if (n >= NODES) return;
    int tot = 0;
    int p[8];
    #pragma unroll
    for (int x = 0; x < 8; ++x) {
        p[x] = tot;
        tot += cntx[(size_t)x * NODES + n];
    }
    #pragma unroll
    for (int x = 0; x < 8; ++x)
        cntx[(size_t)x * NODES + n] = p[x];
    cnt[n] = tot;
}

__global__ void scan1_k(const int* __restrict__ cnt, int* __restrict__ rowptr,
                        int* __restrict__ bsum)
{
    __shared__ int s[256];
    int tid = threadIdx.x;
    int i = blockIdx.x * 256 + tid;
    int v = (i < NODES) ? cnt[i] : 0;
    s[tid] = v;
    __syncthreads();
    for (int off = 1; off < 256; off <<= 1) {
        int t = (tid >= off) ? s[tid - off] : 0;
        __syncthreads();
        s[tid] += t;
        __syncthreads();
    }
    if (i < NODES) rowptr[i] = s[tid] - v;
    if (tid == 255) bsum[blockIdx.x] = s[255];
}

__global__ void scan2_k(const int* __restrict__ bsum, int* __restrict__ boffs, int nb)
{
    __shared__ int s[512];
    int tid = threadIdx.x;
    int v = (tid < nb) ? bsum[tid] : 0;
    s[tid] = v;
    __syncthreads();
    for (int off = 1; off < 512; off <<= 1) {
        int t = (tid >= off) ? s[tid - off] : 0;
        __syncthreads();
        s[tid] += t;
        __syncthreads();
    }
    if (tid < nb) boffs[tid] = s[tid] - v;
}

__global__ void scan3_k(int* __restrict__ rowptr, const int* __restrict__ boffs,
                        const int* __restrict__ cntx, int* __restrict__ curx)
{
    int i = blockIdx.x * 256 + threadIdx.x;
    if (i < NODES) {
        int v = rowptr[i] + boffs[blockIdx.x];
        rowptr[i] = v;
        #pragma unroll
        for (int x = 0; x < 8; ++x)
            curx[(size_t)x * NODES + i] = v + cntx[(size_t)x * NODES + i];
    }
    if (i == 0) rowptr[NODES] = EDGES;
}

__global__ void posfill_k(const int* __restrict__ dst, int* __restrict__ curx,
                          int* __restrict__ pos)
{
    int t = blockIdx.x * 256 + threadIdx.x;
    if (t >= EDGES / 4) return;
    int4 d = ((const int4*)dst)[t];
    int* cur = curx + (size_t)(blockIdx.x & 7) * NODES;
    int4 p;
    p.x = atomicAdd(&cur[d.x], 1);
    p.y = atomicAdd(&cur[d.y], 1);
    p.z = atomicAdd(&cur[d.z], 1);
    p.w = atomicAdd(&cur[d.w], 1);
    ((int4*)pos)[t] = p;     // coalesced
}

__global__ void scat_k(const int* __restrict__ src, const int* __restrict__ pos,
                       int* __restrict__ esrc)
{
    int e = blockIdx.x * 256 + threadIdx.x;
    if (e < EDGES) esrc[pos[e]] = src[e];
}

// ---------------------------------------------------------------------------
// Propagation r14: IN-KERNEL PLANE PHASING. z stored as [4][N][16] bf16
// planes (3.2 MB each < 4 MB XCD L2). r13 budget audit: prop = ~510us (59%),
// gather of 205MB/step from a 12.8MB z at ~30% L2 hit. r11's gridDim.y
// plane-split FAILED because both planes' blocks were co-resident (working
// set never shrank). Here: ONE kernel, each block loops p=0..3 in program
// order; per-block work ≈ 1024 edges ± 3% (Poisson(16) x 64 rows) -> blocks
// stay phase-aligned without sync -> per-phase gather set = one read-only
// 3.2MB plane -> replicates into every XCD L2 -> L2-rate gather.
// Geometry: 4 lanes/row x 8B AGENT-scope atomic loads (L1-MSHR bypass, r4),
// 16 outstanding/lane per strip. Per-column edge order unchanged ->
// bitwise-identical output. esrc re-read 4x (block's slice is L2-hot after
// phase 0).
// ---------------------------------------------------------------------------
__global__ __launch_bounds__(256)
void prop_k(const int* __restrict__ rowptr, const int* __restrict__ esrc,
            const unsigned long long* __restrict__ zin, const float* __restrict__ logits,
            unsigned long long* __restrict__ zout)
{
    int row = blockIdx.x * 64 + (threadIdx.x >> 2);
    if (row >= NODES) return;
    int l4 = threadIdx.x & 3;
    int beg = rowptr[row], end = rowptr[row + 1];
    float dg = (float)(end - beg);
    float cc = (1.f - ALPHA_C) / fmaxf(dg, 1.f);

    #pragma unroll 1
    for (int p = 0; p < 4; ++p) {
        const unsigned long long* zp = zin + (size_t)p * NODES * 4;  // 32 B/row
        float a0 = 0.f, a1 = 0.f, a2 = 0.f, a3 = 0.f;

        for (int cbeg = beg; cbeg < end; cbeg += 16) {
            int cnt = min(16, end - cbeg);
            int eb = cbeg + l4 * 4;
            int s0 = (eb     < end) ? esrc[eb]     : 0;
            int s1 = (eb + 1 < end) ? esrc[eb + 1] : 0;
            int s2 = (eb + 2 < end) ? esrc[eb + 2] : 0;
            int s3 = (eb + 3 < end) ? esrc[eb + 3] : 0;
            if (cnt == 16) {
                int idx[16];
                #pragma unroll
                for (int j = 0; j < 16; ++j) {
                    int sv = (j & 3) == 0 ? s0 : (j & 3) == 1 ? s1 : (j & 3) == 2 ? s2 : s3;
                    idx[j] = __shfl(sv, j >> 2, 4);
                }
                unsigned long long vv[16];
                #pragma unroll
                for (int j = 0; j < 16; ++j)
                    vv[j] = __hip_atomic_load(zp + (size_t)idx[j] * 4 + l4,
                                              __ATOMIC_RELAXED, __HIP_MEMORY_SCOPE_AGENT);
                #pragma unroll
                for (int j = 0; j < 16; ++j) {
                    unsigned int lo = (unsigned int)vv[j];
                    unsigned int hi = (unsigned int)(vv[j] >> 32);
                    a0 += asf(lo << 16);  a1 += asf(lo & 0xffff0000u);
                    a2 += asf(hi << 16);  a3 += asf(hi & 0xffff0000u);
                }
            } else {
                for (int j = 0; j < cnt; ++j) {
                    int sv = (j & 3) == 0 ? s0 : (j & 3) == 1 ? s1 : (j & 3) == 2 ? s2 : s3;
                    int id = __shfl(sv, j >> 2, 4);
                    unsigned long long v = __hip_atomic_load(zp + (size_t)id * 4 + l4,
                                                             __ATOMIC_RELAXED, __HIP_MEMORY_SCOPE_AGENT);
                    unsigned int lo = (unsigned int)v;
                    unsigned int hi = (unsigned int)(v >> 32);
                    a0 += asf(lo << 16);  a1 += asf(lo & 0xffff0000u);
                    a2 += asf(hi << 16);  a3 += asf(hi & 0xffff0000u);
                }
            }
        }

        const float* lp = logits + (size_t)row * CLS + p * 16 + l4 * 4;
        float4 lv = *(const float4*)lp;
        float r0 = cc * a0 + ALPHA_C * lv.x;
        float r1 = cc * a1 + ALPHA_C * lv.y;
        float r2 = cc * a2 + ALPHA_C * lv.z;
        float r3 = cc * a3 + ALPHA_C * lv.w;
        unsigned int w0 = ((unsigned int)f2b(r1) << 16) | (unsigned int)f2b(r0);
        unsigned int w1 = ((unsigned int)f2b(r3) << 16) | (unsigned int)f2b(r2);
        zout[(size_t)p * NODES * 4 + (size_t)row * 4 + l4] =
            ((unsigned long long)w1 << 32) | w0;
    }
}

// ---------------------------------------------------------------------------
// log_softmax over C=64 (one wave wide), bf16 4-PLANE input, fp32 out
// ---------------------------------------------------------------------------
__global__ __launch_bounds__(256)
void logsoftmax_k(const unsigned short* __restrict__ z, float* __restrict__ out)
{
    int row = blockIdx.x * 4 + (threadIdx.x >> 6);
    if (row >= NODES) return;
    int lane = threadIdx.x & 63;
    float v = b2f(z[((size_t)(lane >> 4) * NODES + row) * 16 + (lane & 15)]);
    float m = v;
    #pragma unroll
    for (int off = 32; off > 0; off >>= 1) m = fmaxf(m, __shfl_xor(m, off, 64));
    float ex = expf(v - m);
    float s = ex;
    #pragma unroll
    for (int off = 32; off > 0; off >>= 1) s += __shfl_xor(s, off, 64);
    out[(size_t)row * CLS + lane] = (v - m) - logf(s);
}

// ---------------------------------------------------------------------------
extern "C" void kernel_launch(void* const* d_in, const int* in_sizes, int n_in,
                              void* d_out, int out_size, void* d_ws, size_t ws_size,
                              hipStream_t stream)
{
    const float* x   = (const float*)d_in[0];
    const int*   src = (const int*)d_in[1];
    const int*   dst = (const int*)d_in[2];
    // d_in[3] = w: reproduced exactly as 1/max(deg,1) from rowptr (validated r3/r4)
    const float* W1  = (const float*)d_in[4];
    const float* b1  = (const float*)d_in[5];
    const float* g1  = (const float*)d_in[6];
    const float* be1 = (const float*)d_in[7];
    const float* W2  = (const float*)d_in[8];
    const float* b2  = (const float*)d_in[9];
    const float* g2  = (const float*)d_in[10];
    const float* be2 = (const float*)d_in[11];
    const float* W3  = (const float*)d_in[12];
    const float* b3  = (const float*)d_in[13];
    const float* zsam = (const float*)d_in[14];
    float* outp = (float*)d_out;

    // ---- workspace layout (~168 MB). A-tensors padded by 128 rows so GEMM
    //      loads are unconditional (pad rows read, never stored). ----
    const int NPAD = NODES + 128;
    uint8_t* base = (uint8_t*)d_ws;
    float* s_scale1 = (float*)(base);
    float* s_shift1 = s_scale1 + 256;
    float* s_scale2 = s_shift1 + 256;
    float* s_shift2 = s_scale2 + 256;
    float* s_sum    = s_shift2 + 256;
    float* s_sq     = s_sum + 256;
    int*   flag     = (int*)(s_sq + 256);

    unsigned short* Wt1 = (unsigned short*)(base + (1 << 14));            // 64 KB
    unsigned short* Wt2 = Wt1 + (size_t)FEAT * HID;                       // 128 KB
    unsigned short* Wt3 = Wt2 + (size_t)HID * HID;                        // 32 KB
    unsigned short* h1  = Wt3 + (size_t)HID * CLS;                        // 51.3 MB (padded)
    unsigned short* h2  = h1 + (size_t)NPAD * HID;                        // 51.3 MB (padded)
    float* logits = (float*)(h2 + (size_t)NPAD * HID);                    // 25.6 MB
    unsigned short* zA  = (unsigned short*)(logits + (size_t)NODES * CLS);// 12.8 MB (4 planes)
    unsigned short* zB  = zA + (size_t)NODES * CLS;                       // 12.8 MB (4 planes)
    int* esrc   = (int*)(zB + (size_t)NODES * CLS);                       // 6.4 MB
    int* cntx   = esrc + EDGES;                                           // 8 x NODES
    int* curx   = cntx + (size_t)8 * NODES;                               // 8 x NODES
    int* rowptr = curx + (size_t)8 * NODES;                               // NODES+1
    int* cnt    = rowptr + (NODES + 1);                                   // NODES
    int* bsum   = cnt + NODES;
    int* boffs  = bsum + 512;
    // pos[] (6.4 MB) aliases h1 (CSR done before GEMM1 writes h1).
    // xb[] (25.7 MB bf16 x, padded) aliases h2 (dead before GEMM2 writes h2).
    int* pos = (int*)h1;
    unsigned short* xb = h2;

    const int NCHUNK2 = (NODES + 63) / 64;      // 1563 (layer 2, 64-row chunks)
    const int NBLK2   = (NCHUNK2 + 1) / 2;      // 782
    const int NCHUNK3 = (NODES + 127) / 128;    // 782 (layer 3, 128-row chunks)
    const int NBLK3   = (NCHUNK3 + 1) / 2;      // 391
    const int NCH1    = (NODES + 31) / 32;      // 3125 (layer 1, 32-row chunks)
    const int NB1     = 512;                    // layer-1 blocks
    const int SCANB   = (NODES + 255) / 256;    // 391
    const int EB4     = (EDGES / 4 + 255) / 256;// 1563

    // ---- pack weights (transposed bf16) + x->bf16; zero A-tensor pad rows ----
    packwt_k<<<(FEAT * HID + 255) / 256, 256, 0, stream>>>(W1, Wt1, FEAT, HID);
    packwt_k<<<(HID * HID + 255) / 256, 256, 0, stream>>>(W2, Wt2, HID, HID);
    packwt_k<<<(HID * CLS + 255) / 256, 256, 0, stream>>>(W3, Wt3, HID, CLS);
    xcvt_k<<<(NODES * FEAT / 8 + 255) / 256, 256, 0, stream>>>(x, xb);
    hipMemsetAsync(h1 + (size_t)NODES * HID, 0, 128 * HID * sizeof(unsigned short), stream);
    hipMemsetAsync(xb + (size_t)NODES * FEAT, 0, 128 * FEAT * sizeof(unsigned short), stream);

    // ---- CSR build ----
    hipMemsetAsync(cntx, 0, (size_t)8 * NODES * sizeof(int), stream);
    count_k<<<EB4, 256, 0, stream>>>(dst, cntx);
    sumoff_k<<<SCANB, 256, 0, stream>>>(cntx, cnt);
    scan1_k<<<SCANB, 256, 0, stream>>>(cnt, rowptr, bsum);
    scan2_k<<<1, 512, 0, stream>>>(bsum, boffs, SCANB);
    scan3_k<<<SCANB, 256, 0, stream>>>(rowptr, boffs, cntx, curx);
    posfill_k<<<EB4, 256, 0, stream>>>(dst, curx, pos);
    scat_k<<<EDGES / 256, 256, 0, stream>>>(src, pos, esrc);

    // ---- Layer 1 (col-split, x read once): h1 = xb @ W1 + b1 ----
    hipMemsetAsync(s_sum, 0, 512 * sizeof(float), stream);
    gemm1_k<<<NB1, 256, 0, stream>>>(xb, Wt1, b1, h1, s_sum, s_sq, NODES, NCH1, NB1);
    bnfin_k<<<1, 256, 0, stream>>>(s_sum, s_sq, g1, be1, s_scale1, s_shift1);

    // ---- Layer 2: h2 = relu(bn(h1)) @ W2 + b2, stats fused (128-col panels) ----
    hipMemsetAsync(s_sum, 0, 512 * sizeof(float), stream);
    gemm_lds_k<true, true, false, HID, 2, 128><<<NBLK2 * 2, 256, 0, stream>>>(
        h1, Wt2, b2, s_scale1, s_shift1, h2, s_sum, s_sq, NODES, HID, NCHUNK2, NBLK2);
    bnfin_k<<<1, 256, 0, stream>>>(s_sum, s_sq, g2, be2, s_scale2, s_shift2);
    hipMemsetAsync(h2 + (size_t)NODES * HID, 0, 128 * HID * sizeof(unsigned short), stream);

    // ---- Layer 3: logits fp32, N=64 ----
    gemm_lds_k<true, false, true, HID, 1, 64><<<NBLK3, 256, 0, stream>>>(
        h2, Wt3, b3, s_scale2, s_shift2, logits, nullptr, nullptr, NODES, CLS, NCHUNK3, NBLK3);

    // ---- warm-start blend into zA (4-plane layout) ----
    hipMemsetAsync(flag, 0, sizeof(int), stream);
    flag_k<<<(NODES * CLS + 255) / 256, 256, 0, stream>>>(zsam, flag);
    blend_k<<<(NODES * CLS + 255) / 256, 256, 0, stream>>>(zsam, logits, flag, zA);

    // ---- K=10 propagation steps, ping-pong zA <-> zB, plane-phased ----
    const int PROPB = (NODES + 63) / 64;
    for (int it = 0; it < KPROP; ++it) {
        const unsigned long long* zi = (const unsigned long long*)((it & 1) ? zB : zA);
        unsigned long long* zo = (unsigned long long*)((it & 1) ? zA : zB);
        prop_k<<<PROPB, 256, 0, stream>>>(rowptr, esrc, zi, logits, zo);
    }
    // KPROP even -> final in zA

    // ---- log_softmax -> d_out ----
    logsoftmax_k<<<(NODES + 3) / 4, 256, 0, stream>>>(zA, outp);
}

// Round 11
// 861.786 us; speedup vs baseline: 1.3463x; 1.3463x over previous
//
#include <hip/hip_runtime.h>
#include <hip/hip_bf16.h>

// Problem constants (match reference)
#define NODES 100000
#define EDGES 1600000
#define FEAT  128
#define HID   256
#define CLS   64
#define KPROP 10
#define ALPHA_C 0.1f
#define BETA_C  0.5f
#define BN_EPS  1e-5f

typedef __attribute__((ext_vector_type(8))) short short8;
typedef __attribute__((ext_vector_type(4))) float f32x4;

static __device__ __forceinline__ unsigned short f2b(float f) {
    __hip_bfloat16 h = __float2bfloat16(f);
    return *(unsigned short*)&h;
}
static __device__ __forceinline__ float b2f(unsigned short u) {
    __hip_bfloat16 h;
    *(unsigned short*)&h = u;
    return __bfloat162float(h);
}
static __device__ __forceinline__ float asf(unsigned int u) {
    union { unsigned int u; float f; } c; c.u = u; return c.f;
}
// async global->LDS, 16B/lane. Loads are side-effect instrs: cannot be sunk
// by the scheduler, consume no VGPRs (the r11-r13 register-double-buffer
// failure mode). Dest must be linear (wave-uniform base + lane*16).
static __device__ __forceinline__ void gl_lds16(const void* g, void* l) {
    __builtin_amdgcn_global_load_lds(
        (const __attribute__((address_space(1))) unsigned int*)g,
        (__attribute__((address_space(3))) unsigned int*)l, 16, 0, 0);
}

// ---------------------------------------------------------------------------
// Pack W [K,N] fp32 -> Wt [N,K] bf16 (transposed, for B-fragment loads)
// ---------------------------------------------------------------------------
__global__ void packwt_k(const float* __restrict__ W, unsigned short* __restrict__ Wt,
                         int K, int N)
{
    int i = blockIdx.x * 256 + threadIdx.x;
    if (i < K * N) {
        int k = i / N, n = i - k * N;
        Wt[(size_t)n * K + k] = f2b(W[i]);
    }
}

// x fp32 [N][128] -> xb bf16 (8 elems/thread)
__global__ void xcvt_k(const float* __restrict__ x, unsigned short* __restrict__ xb)
{
    int i = blockIdx.x * 256 + threadIdx.x;
    if (i < NODES * FEAT / 8) {
        float4 a = ((const float4*)x)[2 * i];
        float4 b = ((const float4*)x)[2 * i + 1];
        short8 o;
        o[0] = (short)f2b(a.x); o[1] = (short)f2b(a.y);
        o[2] = (short)f2b(a.z); o[3] = (short)f2b(a.w);
        o[4] = (short)f2b(b.x); o[5] = (short)f2b(b.y);
        o[6] = (short)f2b(b.z); o[7] = (short)f2b(b.w);
        ((short8*)xb)[i] = o;
    }
}

// ---------------------------------------------------------------------------
// Layer-1 GEMM (r11 structure + r13 unconditional loads; below top-5).
// ---------------------------------------------------------------------------
__global__ __launch_bounds__(256, 2)
void gemm1_k(const unsigned short* __restrict__ xb, const unsigned short* __restrict__ Wt,
             const float* __restrict__ bias, unsigned short* __restrict__ h1,
             float* __restrict__ gsum, float* __restrict__ gsq,
             int M, int nchunks, int nblk)
{
    __shared__ unsigned short Blds[256 * FEAT];   // 64 KB
    const int lane = threadIdx.x & 63;
    const int wv   = threadIdx.x >> 6;
    const int quad = lane >> 4;
    const int l16  = lane & 15;
    const int colbase = wv * 64;

    #pragma unroll
    for (int i0 = 0; i0 < 4096; i0 += 256) {
        int i  = i0 + threadIdx.x;
        int c  = i >> 4;
        int k8 = i & 15;
        short8 v = *(const short8*)(Wt + (size_t)c * FEAT + k8 * 8);
        int byte = c * 256 + ((k8 * 16) ^ ((c & 7) << 4));
        *(short8*)((char*)Blds + byte) = v;
    }
    __syncthreads();

    float bcol[4];
    #pragma unroll
    for (int ct = 0; ct < 4; ++ct) bcol[ct] = bias[colbase + ct * 16 + l16];
    float ps[4] = {0.f, 0.f, 0.f, 0.f};
    float pq[4] = {0.f, 0.f, 0.f, 0.f};

    short8 ah0[2][4], ah1[2][4];

#define LOAD1(AH, CHK)                                                         \
    if ((CHK) < nchunks) {                                                     \
        const int rb_ = (CHK) * 32;                                            \
        _Pragma("unroll")                                                      \
        for (int rt = 0; rt < 2; ++rt) {                                       \
            const int row_ = rb_ + rt * 16 + l16;                              \
            const unsigned short* ap_ = xb + (size_t)row_ * FEAT + quad * 8;   \
            _Pragma("unroll")                                                  \
            for (int ks = 0; ks < 4; ++ks)                                     \
                AH[rt][ks] = *(const short8*)(ap_ + ks * 32);                  \
        }                                                                      \
    }

#define COMP1(AH, CHK)                                                         \
    {                                                                          \
        const int rb_ = (CHK) * 32;                                            \
        f32x4 acc[2][4];                                                       \
        _Pragma("unroll")                                                      \
        for (int i = 0; i < 2; ++i)                                            \
            _Pragma("unroll")                                                  \
            for (int j = 0; j < 4; ++j)                                        \
                acc[i][j] = (f32x4){0.f, 0.f, 0.f, 0.f};                       \
        _Pragma("unroll")                                                      \
        for (int ks = 0; ks < 4; ++ks) {                                       \
            _Pragma("unroll")                                                  \
            for (int ct = 0; ct < 4; ++ct) {                                   \
                const int col_ = colbase + ct * 16 + l16;                      \
                const int boff = col_ * 256                                    \
                               + ((ks * 64 + quad * 16) ^ ((col_ & 7) << 4));  \
                short8 bf = *(const short8*)((const char*)Blds + boff);        \
                acc[0][ct] = __builtin_amdgcn_mfma_f32_16x16x32_bf16(AH[0][ks], bf, acc[0][ct], 0, 0, 0); \
                acc[1][ct] = __builtin_amdgcn_mfma_f32_16x16x32_bf16(AH[1][ks], bf, acc[1][ct], 0, 0, 0); \
            }                                                                  \
        }                                                                      \
        _Pragma("unroll")                                                      \
        for (int ct = 0; ct < 4; ++ct) {                                       \
            const int col_ = colbase + ct * 16 + l16;                          \
            _Pragma("unroll")                                                  \
            for (int rt = 0; rt < 2; ++rt) {                                   \
                _Pragma("unroll")                                              \
                for (int r2 = 0; r2 < 4; ++r2) {                               \
                    const int row_ = rb_ + rt * 16 + quad * 4 + r2;            \
                    if (row_ < M) {                                            \
                        float vv = acc[rt][ct][r2] + bcol[ct];                 \
                        ps[ct] += vv; pq[ct] += vv * vv;                       \
                        h1[(size_t)row_ * HID + col_] = f2b(vv);               \
                    }                                                          \
                }                                                              \
            }                                                                  \
        }                                                                      \
    }

    int chunk = blockIdx.x;
    LOAD1(ah0, chunk)
    while (chunk < nchunks) {
        const int cn1 = chunk + nblk;
        LOAD1(ah1, cn1)
        __builtin_amdgcn_sched_barrier(0);
        COMP1(ah0, chunk)
        chunk = cn1;
        if (chunk >= nchunks) break;
        const int cn2 = chunk + nblk;
        LOAD1(ah0, cn2)
        __builtin_amdgcn_sched_barrier(0);
        COMP1(ah1, chunk)
        chunk = cn2;
    }
#undef LOAD1
#undef COMP1

    #pragma unroll
    for (int ct = 0; ct < 4; ++ct) {
        float s = ps[ct];
        s += __shfl_xor(s, 16, 64);
        s += __shfl_xor(s, 32, 64);
        float q = pq[ct];
        q += __shfl_xor(q, 16, 64);
        q += __shfl_xor(q, 32, 64);
        if (lane < 16) {
            atomicAdd(&gsum[colbase + ct * 16 + lane], s);
            atomicAdd(&gsq[colbase + ct * 16 + lane], q);
        }
    }
}

// ---------------------------------------------------------------------------
// Layer-2 GEMM r15: ASYNC LDS STAGING. r11-r13 PMC arc: the register A
// double-buffer is always sunk by the allocator (VGPR 116/80/88, MfmaUtil
// 6-7%) -> latency-bound at ~70us. global_load_lds loads are side-effect
// instructions: un-sinkable, zero VGPR. Block = 512 thr (8 waves), tile
// 64 rows x 128 cols; LDS: B 64KB + A dbuf 2x32KB = 133KB (1 blk/CU).
// A staged with PRE-SWIZZLED GLOBAL SOURCE (dest must be linear; m173
// pattern): LDS[P] = A[P ^ ((P>>9 &7)<<4)], reader applies same XOR ->
// conflict-light ds_read_b128. m97 schedule: barrier -> issue next chunk's
// loads -> compute current (loads fly under FUSE+MFMA).
// ---------------------------------------------------------------------------
__global__ __launch_bounds__(512, 1)
void gemm2_k(const unsigned short* __restrict__ Ain, const unsigned short* __restrict__ Wt,
             const float* __restrict__ bias,
             const float* __restrict__ scale, const float* __restrict__ shift,
             unsigned short* __restrict__ outp,
             float* __restrict__ gsum, float* __restrict__ gsq,
             int M, int nchunks, int nblk)
{
    __shared__ unsigned short Blds[128 * HID];    // 64 KB
    __shared__ unsigned short Alds[2][64 * HID];  // 2 x 32 KB
    __shared__ float Slds[HID];
    __shared__ float Hlds[HID];

    const int tid  = threadIdx.x;
    const int lane = tid & 63;
    const int wv   = tid >> 6;          // 0..7
    const int quad = lane >> 4;
    const int l16  = lane & 15;
    const int ch   = wv & 1;            // col half (0,1) -> 64 cols
    const int rg   = wv >> 1;           // row group (0..3) -> 16 rows
    const int colg = blockIdx.x & 1;
    const int blk0 = blockIdx.x >> 1;
    const int colpan = colg * 128;

    // ---- stage B panel (128 cols x 256 K, swizzled) + scale/shift ----
    {
        const unsigned short* wp = Wt + (size_t)colpan * HID;
        #pragma unroll
        for (int i0 = 0; i0 < 4096; i0 += 512) {
            int i  = i0 + tid;
            int c  = i >> 5;            // / (HID/8)
            int k8 = i & 31;
            short8 v = *(const short8*)(wp + (size_t)c * HID + k8 * 8);
            int byte = c * 512 + ((k8 * 16) ^ ((c & 7) << 4));
            *(short8*)((char*)Blds + byte) = v;
        }
        if (tid < HID) { Slds[tid] = scale[tid]; Hlds[tid] = shift[tid]; }
    }

    float bcol[4];
    #pragma unroll
    for (int ct = 0; ct < 4; ++ct) bcol[ct] = bias[colpan + ch * 64 + ct * 16 + l16];
    float ps[4] = {0.f, 0.f, 0.f, 0.f};
    float pq[4] = {0.f, 0.f, 0.f, 0.f};

#define STAGE2(BUF, CHK)                                                       \
    if ((CHK) < nchunks) {                                                     \
        const char* abase = (const char*)Ain + (size_t)(CHK) * 64 * 512;       \
        char* lbase = (char*)Alds[BUF];                                        \
        _Pragma("unroll")                                                      \
        for (int j = 0; j < 4; ++j) {                                          \
            const int P = j * 8192 + tid * 16;                                 \
            const int L = P ^ (((P >> 9) & 7) << 4);                           \
            gl_lds16(abase + L, lbase + P);                                    \
        }                                                                      \
    }

#define COMP2(BUF, CHK)                                                        \
    {                                                                          \
        f32x4 acc[4];                                                          \
        _Pragma("unroll")                                                      \
        for (int j = 0; j < 4; ++j) acc[j] = (f32x4){0.f, 0.f, 0.f, 0.f};      \
        const int row_l = rg * 16 + l16;                                       \
        const char* albase = (const char*)Alds[BUF];                           \
        _Pragma("unroll")                                                      \
        for (int gks = 0; gks < 8; ++gks) {                                    \
            const int k_ = gks * 32 + quad * 8;                                \
            float4 s0 = *(const float4*)&Slds[k_];                             \
            float4 s1 = *(const float4*)&Slds[k_ + 4];                         \
            float4 h0 = *(const float4*)&Hlds[k_];                             \
            float4 h1v = *(const float4*)&Hlds[k_ + 4];                        \
            const int aoff = row_l * 512                                       \
                           + ((gks * 64 + quad * 16) ^ ((row_l & 7) << 4));    \
            short8 ar = *(const short8*)(albase + aoff);                       \
            float v[8];                                                        \
            _Pragma("unroll")                                                  \
            for (int j = 0; j < 8; ++j) v[j] = b2f((unsigned short)ar[j]);     \
            v[0] = fmaxf(fmaf(v[0], s0.x, h0.x), 0.f);                         \
            v[1] = fmaxf(fmaf(v[1], s0.y, h0.y), 0.f);                         \
            v[2] = fmaxf(fmaf(v[2], s0.z, h0.z), 0.f);                         \
            v[3] = fmaxf(fmaf(v[3], s0.w, h0.w), 0.f);                         \
            v[4] = fmaxf(fmaf(v[4], s1.x, h1v.x), 0.f);                        \
            v[5] = fmaxf(fmaf(v[5], s1.y, h1v.y), 0.f);                        \
            v[6] = fmaxf(fmaf(v[6], s1.z, h1v.z), 0.f);                        \
            v[7] = fmaxf(fmaf(v[7], s1.w, h1v.w), 0.f);                        \
            short8 a2;                                                         \
            _Pragma("unroll")                                                  \
            for (int j = 0; j < 8; ++j) a2[j] = (short)f2b(v[j]);              \
            _Pragma("unroll")                                                  \
            for (int ct = 0; ct < 4; ++ct) {                                   \
                const int lc = ch * 64 + ct * 16 + l16;                        \
                const int boff = lc * 512                                      \
                               + ((gks * 64 + quad * 16) ^ ((l16 & 7) << 4));  \
                short8 bf = *(const short8*)((const char*)Blds + boff);        \
                acc[ct] = __builtin_amdgcn_mfma_f32_16x16x32_bf16(a2, bf, acc[ct], 0, 0, 0); \
            }                                                                  \
        }                                                                      \
        const int rb_ = (CHK) * 64 + rg * 16;                                  \
        _Pragma("unroll")                                                      \
        for (int ct = 0; ct < 4; ++ct) {                                       \
            const int col_ = colpan + ch * 64 + ct * 16 + l16;                 \
            _Pragma("unroll")                                                  \
            for (int r2 = 0; r2 < 4; ++r2) {                                   \
                const int row_ = rb_ + quad * 4 + r2;                          \
                if (row_ < M) {                                                \
                    float vv = acc[ct][r2] + bcol[ct];                         \
                    ps[ct] += vv; pq[ct] += vv * vv;                           \
                    outp[(size_t)row_ * HID + col_] = f2b(vv);                 \
                }                                                              \
            }                                                                  \
        }                                                                      \
    }

    int c = blk0, buf = 0;
    STAGE2(0, c)
    while (c < nchunks) {
        __syncthreads();                 // drains A(buf) loads (flew under prev compute)
        const int cn = c + nblk;
        if (buf == 0) { STAGE2(1, cn) } else { STAGE2(0, cn) }
        COMP2(buf, c)
        c = cn;
        buf ^= 1;
    }
#undef STAGE2
#undef COMP2

    #pragma unroll
    for (int ct = 0; ct < 4; ++ct) {
        float s = ps[ct];
        s += __shfl_xor(s, 16, 64);
        s += __shfl_xor(s, 32, 64);
        float q = pq[ct];
        q += __shfl_xor(q, 16, 64);
        q += __shfl_xor(q, 32, 64);
        if (lane < 16) {
            atomicAdd(&gsum[colpan + ch * 64 + ct * 16 + lane], s);
            atomicAdd(&gsq[colpan + ch * 64 + ct * 16 + lane], q);
        }
    }
}

// ---------------------------------------------------------------------------
// GEMM v5 (layer 3; r13). Unconditional A loads (padded A), 64-col panel,
// half-chunk pipelining.
// ---------------------------------------------------------------------------
template<bool FUSE, bool STATS, bool OUTF32, int KK, int NCOLG, int COLS>
__global__ __launch_bounds__(256, 2)
void gemm_lds_k(const unsigned short* __restrict__ Ain, const unsigned short* __restrict__ Wt,
                const float* __restrict__ bias,
                const float* __restrict__ scale, const float* __restrict__ shift,
                void* __restrict__ outp,
                float* __restrict__ gsum, float* __restrict__ gsq,
                int M, int N, int nchunks, int nblk)
{
    constexpr int NK8 = KK / 32;
    constexpr int NKH = NK8 / 2;                 // ks per half-chunk
    constexpr int CHROWS = (COLS == 128) ? 64 : 128;
    __shared__ unsigned short Blds[COLS * KK];
    __shared__ float Slds[KK];
    __shared__ float Hlds[KK];

    const int lane = threadIdx.x & 63;
    const int wv   = threadIdx.x >> 6;
    const int quad = lane >> 4;
    const int l16  = lane & 15;
    const int colg = (NCOLG > 1) ? (blockIdx.x % NCOLG) : 0;
    const int blk0 = (NCOLG > 1) ? (blockIdx.x / NCOLG) : blockIdx.x;
    const int colpan = colg * COLS;
    const int lwcol  = (COLS == 128) ? (wv & 1) * 64 : 0;
    const int rwoff  = (COLS == 128) ? (wv >> 1) * 32 : wv * 32;

    {
        const unsigned short* wp = Wt + (size_t)colpan * KK;
        constexpr int ELEMS = COLS * KK / 8;
        #pragma unroll
        for (int i0 = 0; i0 < ELEMS; i0 += 256) {
            int i  = i0 + threadIdx.x;
            int c  = i / (KK / 8);
            int k8 = i - c * (KK / 8);
            short8 v = *(const short8*)(wp + (size_t)c * KK + k8 * 8);
            int byte = c * (KK * 2) + ((k8 * 16) ^ ((c & 7) << 4));
            *(short8*)((char*)Blds + byte) = v;
        }
        if constexpr (FUSE) {
            for (int i = threadIdx.x; i < KK; i += 256) {
                Slds[i] = scale[i];
                Hlds[i] = shift[i];
            }
        }
    }
    __syncthreads();

    float bcol[4];
    #pragma unroll
    for (int ct = 0; ct < 4; ++ct) bcol[ct] = bias[colpan + lwcol + ct * 16 + l16];

    float ps[4] = {0.f, 0.f, 0.f, 0.f};
    float pq[4] = {0.f, 0.f, 0.f, 0.f};

    short8 hb0[2][NKH], hb1[2][NKH];
    f32x4 acc[2][4];

#define LOADH(B, CHK, H)                                                       \
    if ((CHK) < nchunks) {                                                     \
        const int rb_ = (CHK) * CHROWS + rwoff;                                \
        _Pragma("unroll")                                                      \
        for (int rt = 0; rt < 2; ++rt) {                                       \
            const int row_ = rb_ + rt * 16 + l16;                              \
            const unsigned short* ap_ = Ain + (size_t)row_ * KK                \
                                        + (H) * NKH * 32 + quad * 8;           \
            _Pragma("unroll")                                                  \
            for (int ks = 0; ks < NKH; ++ks)                                   \
                B[rt][ks] = *(const short8*)(ap_ + ks * 32);                   \
        }                                                                      \
    }

#define COMPH(B, H)                                                            \
    {                                                                          \
        _Pragma("unroll")                                                      \
        for (int ks = 0; ks < NKH; ++ks) {                                     \
            const int gks = (H) * NKH + ks;                                    \
            const int k_ = gks * 32 + quad * 8;                                \
            float sc[8], sh[8];                                                \
            if constexpr (FUSE) {                                              \
                float4 s0 = *(const float4*)&Slds[k_];                         \
                float4 s1 = *(const float4*)&Slds[k_ + 4];                     \
                float4 h0 = *(const float4*)&Hlds[k_];                         \
                float4 h1 = *(const float4*)&Hlds[k_ + 4];                     \
                sc[0]=s0.x; sc[1]=s0.y; sc[2]=s0.z; sc[3]=s0.w;                \
                sc[4]=s1.x; sc[5]=s1.y; sc[6]=s1.z; sc[7]=s1.w;                \
                sh[0]=h0.x; sh[1]=h0.y; sh[2]=h0.z; sh[3]=h0.w;                \
                sh[4]=h1.x; sh[5]=h1.y; sh[6]=h1.z; sh[7]=h1.w;                \
            }                                                                  \
            short8 a2[2];                                                      \
            _Pragma("unroll")                                                  \
            for (int rt = 0; rt < 2; ++rt) {                                   \
                if constexpr (FUSE) {                                          \
                    float v[8];                                                \
                    _Pragma("unroll")                                          \
                    for (int j = 0; j < 8; ++j)                                \
                        v[j] = b2f((unsigned short)B[rt][ks][j]);              \
                    _Pragma("unroll")                                          \
                    for (int j = 0; j < 8; ++j)                                \
                        v[j] = fmaxf(fmaf(v[j], sc[j], sh[j]), 0.f);           \
                    short8 av;                                                 \
                    _Pragma("unroll")                                          \
                    for (int j = 0; j < 8; ++j) av[j] = (short)f2b(v[j]);      \
                    a2[rt] = av;                                               \
                } else {                                                       \
                    a2[rt] = B[rt][ks];                                        \
                }                                                              \
            }                                                                  \
            _Pragma("unroll")                                                  \
            for (int ct = 0; ct < 4; ++ct) {                                   \
                const int lc_ = lwcol + ct * 16 + l16;                         \
                const int boff = lc_ * (KK * 2)                                \
                               + ((gks * 64 + quad * 16) ^ ((l16 & 7) << 4));  \
                short8 bf = *(const short8*)((const char*)Blds + boff);        \
                acc[0][ct] = __builtin_amdgcn_mfma_f32_16x16x32_bf16(a2[0], bf, acc[0][ct], 0, 0, 0); \
                acc[1][ct] = __builtin_amdgcn_mfma_f32_16x16x32_bf16(a2[1], bf, acc[1][ct], 0, 0, 0); \
            }                                                                  \
        }                                                                      \
    }

    int chunk = blk0;
    LOADH(hb0, chunk, 0)
    while (chunk < nchunks) {
        #pragma unroll
        for (int i = 0; i < 2; ++i)
            #pragma unroll
            for (int j = 0; j < 4; ++j)
                acc[i][j] = (f32x4){0.f, 0.f, 0.f, 0.f};

        LOADH(hb1, chunk, 1)
        __builtin_amdgcn_sched_barrier(0);
        COMPH(hb0, 0)
        const int nxt = chunk + nblk;
        LOADH(hb0, nxt, 0)
        __builtin_amdgcn_sched_barrier(0);
        COMPH(hb1, 1)

        const int rb_ = chunk * CHROWS + rwoff;
        #pragma unroll
        for (int ct = 0; ct < 4; ++ct) {
            const int col_ = colpan + lwcol + ct * 16 + l16;
            #pragma unroll
            for (int rt = 0; rt < 2; ++rt) {
                #pragma unroll
                for (int r2 = 0; r2 < 4; ++r2) {
                    const int row_ = rb_ + rt * 16 + quad * 4 + r2;
                    if (row_ < M) {
                        float vv = acc[rt][ct][r2] + bcol[ct];
                        if constexpr (STATS) { ps[ct] += vv; pq[ct] += vv * vv; }
                        if constexpr (OUTF32) {
                            ((float*)outp)[(size_t)row_ * N + col_] = vv;
                        } else {
                            ((unsigned short*)outp)[(size_t)row_ * N + col_] = f2b(vv);
                        }
                    }
                }
            }
        }
        chunk = nxt;
    }
#undef LOADH
#undef COMPH

    if constexpr (STATS) {
        #pragma unroll
        for (int ct = 0; ct < 4; ++ct) {
            float s = ps[ct];
            s += __shfl_xor(s, 16, 64);
            s += __shfl_xor(s, 32, 64);
            float q = pq[ct];
            q += __shfl_xor(q, 16, 64);
            q += __shfl_xor(q, 32, 64);
            if (lane < 16) {
                atomicAdd(&gsum[colpan + lwcol + ct * 16 + lane], s);
                atomicAdd(&gsq[colpan + lwcol + ct * 16 + lane], q);
            }
        }
    }
}

__global__ void bnfin_k(const float* __restrict__ sum, const float* __restrict__ sq,
                        const float* __restrict__ g, const float* __restrict__ be,
                        float* __restrict__ scale, float* __restrict__ shift)
{
    int c = threadIdx.x;  // 256
    float mu = sum[c] * (1.f / NODES);
    float var = sq[c] * (1.f / NODES) - mu * mu;
    float sc = g[c] * rsqrtf(var + BN_EPS);
    scale[c] = sc;
    shift[c] = be[c] - mu * sc;
}

// ---------------------------------------------------------------------------
// use_x flag: any nonzero in z_sam -> flag=1 (flag pre-zeroed)
// ---------------------------------------------------------------------------
__global__ void flag_k(const float* __restrict__ zs, int* __restrict__ flag)
{
    int i = blockIdx.x * 256 + threadIdx.x;
    bool nz = (i < NODES * CLS) && (zs[i] != 0.f);
    if (__any(nz)) {
        if ((threadIdx.x & 63) == 0) *flag = 1;
    }
}

// z0 (bf16 flat [N][64]) = flag ? (1-beta)*z_sam + beta*logits : logits
__global__ void blend_k(const float* __restrict__ zs, const float* __restrict__ logits,
                        const int* __restrict__ flag, unsigned short* __restrict__ z0)
{
    int i = blockIdx.x * 256 + threadIdx.x;
    if (i < NODES * CLS) {
        float l = logits[i];
        float v = (*flag) ? ((1.f - BETA_C) * zs[i] + BETA_C * l) : l;
        z0[i] = f2b(v);
    }
}

// ---------------------------------------------------------------------------
// CSR build (r10 validated): replicated counters; pos/scatter split.
// ---------------------------------------------------------------------------
__global__ void count_k(const int* __restrict__ dst, int* __restrict__ cntx)
{
    int t = blockIdx.x * 256 + threadIdx.x;
    if (t >= EDGES / 4) return;
    int4 d = ((const int4*)dst)[t];
    int* c = cntx + (size_t)(blockIdx.x & 7) * NODES;
    atomicAdd(&c[d.x], 1);
    atomicAdd(&c[d.y], 1);
    atomicAdd(&c[d.z], 1);
    atomicAdd(&c[d.w], 1);
}

__global__ void sumoff_k(int* __restrict__ cntx, int* __restrict__ cnt)
{
    int n = blockIdx.x * 256 + threadIdx.x;
    if (n >= NODES) return;
    int tot = 0;
    int p[8];
    #pragma unroll
    for (int x = 0; x < 8; ++x) {
        p[x] = tot;
        tot += cntx[(size_t)x * NODES + n];
    }
    #pragma unroll
    for (int x = 0; x < 8; ++x)
        cntx[(size_t)x * NODES + n] = p[x];
    cnt[n] = tot;
}

__global__ void scan1_k(const int* __restrict__ cnt, int* __restrict__ rowptr,
                        int* __restrict__ bsum)
{
    __shared__ int s[256];
    int tid = threadIdx.x;
    int i = blockIdx.x * 256 + tid;
    int v = (i < NODES) ? cnt[i] : 0;
    s[tid] = v;
    __syncthreads();
    for (int off = 1; off < 256; off <<= 1) {
        int t = (tid >= off) ? s[tid - off] : 0;
        __syncthreads();
        s[tid] += t;
        __syncthreads();
    }
    if (i < NODES) rowptr[i] = s[tid] - v;
    if (tid == 255) bsum[blockIdx.x] = s[255];
}

__global__ void scan2_k(const int* __restrict__ bsum, int* __restrict__ boffs, int nb)
{
    __shared__ int s[512];
    int tid = threadIdx.x;
    int v = (tid < nb) ? bsum[tid] : 0;
    s[tid] = v;
    __syncthreads();
    for (int off = 1; off < 512; off <<= 1) {
        int t = (tid >= off) ? s[tid - off] : 0;
        __syncthreads();
        s[tid] += t;
        __syncthreads();
    }
    if (tid < nb) boffs[tid] = s[tid] - v;
}

__global__ void scan3_k(int* __restrict__ rowptr, const int* __restrict__ boffs,
                        const int* __restrict__ cntx, int* __restrict__ curx)
{
    int i = blockIdx.x * 256 + threadIdx.x;
    if (i < NODES) {
        int v = rowptr[i] + boffs[blockIdx.x];
        rowptr[i] = v;
        #pragma unroll
        for (int x = 0; x < 8; ++x)
            curx[(size_t)x * NODES + i] = v + cntx[(size_t)x * NODES + i];
    }
    if (i == 0) rowptr[NODES] = EDGES;
}

__global__ void posfill_k(const int* __restrict__ dst, int* __restrict__ curx,
                          int* __restrict__ pos)
{
    int t = blockIdx.x * 256 + threadIdx.x;
    if (t >= EDGES / 4) return;
    int4 d = ((const int4*)dst)[t];
    int* cur = curx + (size_t)(blockIdx.x & 7) * NODES;
    int4 p;
    p.x = atomicAdd(&cur[d.x], 1);
    p.y = atomicAdd(&cur[d.y], 1);
    p.z = atomicAdd(&cur[d.z], 1);
    p.w = atomicAdd(&cur[d.w], 1);
    ((int4*)pos)[t] = p;     // coalesced
}

__global__ void scat_k(const int* __restrict__ src, const int* __restrict__ pos,
                       int* __restrict__ esrc)
{
    int e = blockIdx.x * 256 + threadIdx.x;
    if (e < EDGES) esrc[pos[e]] = src[e];
}

// ---------------------------------------------------------------------------
// Propagation (r10 version, validated best-of-4). 8 lanes per row (lane owns
// 8 bf16 cols as 2x8B), 32 rows per block; full strips = 32 outstanding
// loads/wave. RELAXED/AGENT atomic loads (L1-MSHR bypass, r4).
// ---------------------------------------------------------------------------
__global__ __launch_bounds__(256)
void prop_k(const int* __restrict__ rowptr, const int* __restrict__ esrc,
            const unsigned long long* __restrict__ zin, const float* __restrict__ logits,
            uint4* __restrict__ zout)
{
    int row = blockIdx.x * 32 + (threadIdx.x >> 3);
    if (row >= NODES) return;
    int l8 = threadIdx.x & 7;
    int beg = rowptr[row], end = rowptr[row + 1];
    float a0 = 0.f, a1 = 0.f, a2 = 0.f, a3 = 0.f;
    float a4 = 0.f, a5 = 0.f, a6 = 0.f, a7 = 0.f;

    for (int cbeg = beg; cbeg < end; cbeg += 16) {
        int e0 = cbeg + l8, e1 = cbeg + 8 + l8;
        int s0 = (e0 < end) ? esrc[e0] : 0;
        int s1 = (e1 < end) ? esrc[e1] : 0;
        int cnt = min(16, end - cbeg);
        if (cnt == 16) {
            int idx[16];
            #pragma unroll
            for (int u = 0; u < 8; ++u) idx[u] = __shfl(s0, u, 8);
            #pragma unroll
            for (int u = 0; u < 8; ++u) idx[8 + u] = __shfl(s1, u, 8);
            unsigned long long vv[32];
            #pragma unroll
            for (int u = 0; u < 16; ++u) {
                const unsigned long long* p = zin + (size_t)idx[u] * 16 + l8 * 2;
                vv[2 * u]     = __hip_atomic_load(p,     __ATOMIC_RELAXED, __HIP_MEMORY_SCOPE_AGENT);
                vv[2 * u + 1] = __hip_atomic_load(p + 1, __ATOMIC_RELAXED, __HIP_MEMORY_SCOPE_AGENT);
            }
            #pragma unroll
            for (int u = 0; u < 16; ++u) {
                unsigned int x0 = (unsigned int)vv[2 * u];
                unsigned int x1 = (unsigned int)(vv[2 * u] >> 32);
                unsigned int x2 = (unsigned int)vv[2 * u + 1];
                unsigned int x3 = (unsigned int)(vv[2 * u + 1] >> 32);
                a0 += asf(x0 << 16);  a1 += asf(x0 & 0xffff0000u);
                a2 += asf(x1 << 16);  a3 += asf(x1 & 0xffff0000u);
                a4 += asf(x2 << 16);  a5 += asf(x2 & 0xffff0000u);
                a6 += asf(x3 << 16);  a7 += asf(x3 & 0xffff0000u);
            }
        } else {
            for (int j = 0; j < cnt; ++j) {
                int sv = (j < 8) ? __shfl(s0, j, 8) : __shfl(s1, j - 8, 8);
                const unsigned long long* p = zin + (size_t)sv * 16 + l8 * 2;
                unsigned long long v0 = __hip_atomic_load(p,     __ATOMIC_RELAXED, __HIP_MEMORY_SCOPE_AGENT);
                unsigned long long v1 = __hip_atomic_load(p + 1, __ATOMIC_RELAXED, __HIP_MEMORY_SCOPE_AGENT);
                unsigned int x0 = (unsigned int)v0;
                unsigned int x1 = (unsigned int)(v0 >> 32);
                unsigned int x2 = (unsigned int)v1;
                unsigned int x3 = (unsigned int)(v1 >> 32);
                a0 += asf(x0 << 16);  a1 += asf(x0 & 0xffff0000u);
                a2 += asf(x1 << 16);  a3 += asf(x1 & 0xffff0000u);
                a4 += asf(x2 << 16);  a5 += asf(x2 & 0xffff0000u);
                a6 += asf(x3 << 16);  a7 += asf(x3 & 0xffff0000u);
            }
        }
    }
    float dg = (float)(end - beg);
    float inv = 1.f / fmaxf(dg, 1.f);
    float cc = (1.f - ALPHA_C) * inv;
    const float* lp = logits + (size_t)row * CLS + l8 * 8;
    float4 lv0 = *(const float4*)lp;
    float4 lv1 = *(const float4*)(lp + 4);
    float r0 = cc * a0 + ALPHA_C * lv0.x;
    float r1 = cc * a1 + ALPHA_C * lv0.y;
    float r2 = cc * a2 + ALPHA_C * lv0.z;
    float r3 = cc * a3 + ALPHA_C * lv0.w;
    float r4 = cc * a4 + ALPHA_C * lv1.x;
    float r5 = cc * a5 + ALPHA_C * lv1.y;
    float r6 = cc * a6 + ALPHA_C * lv1.z;
    float r7 = cc * a7 + ALPHA_C * lv1.w;
    uint4 w;
    w.x = ((unsigned int)f2b(r1) << 16) | (unsigned int)f2b(r0);
    w.y = ((unsigned int)f2b(r3) << 16) | (unsigned int)f2b(r2);
    w.z = ((unsigned int)f2b(r5) << 16) | (unsigned int)f2b(r4);
    w.w = ((unsigned int)f2b(r7) << 16) | (unsigned int)f2b(r6);
    zout[(size_t)row * 8 + l8] = w;
}

// ---------------------------------------------------------------------------
// log_softmax over C=64 (one wave wide), bf16 flat input, fp32 out
// ---------------------------------------------------------------------------
__global__ __launch_bounds__(256)
void logsoftmax_k(const unsigned short* __restrict__ z, float* __restrict__ out)
{
    int row = blockIdx.x * 4 + (threadIdx.x >> 6);
    if (row >= NODES) return;
    int lane = threadIdx.x & 63;
    float v = b2f(z[(size_t)row * CLS + lane]);
    float m = v;
    #pragma unroll
    for (int off = 32; off > 0; off >>= 1) m = fmaxf(m, __shfl_xor(m, off, 64));
    float ex = expf(v - m);
    float s = ex;
    #pragma unroll
    for (int off = 32; off > 0; off >>= 1) s += __shfl_xor(s, off, 64);
    out[(size_t)row * CLS + lane] = (v - m) - logf(s);
}

// ---------------------------------------------------------------------------
extern "C" void kernel_launch(void* const* d_in, const int* in_sizes, int n_in,
                              void* d_out, int out_size, void* d_ws, size_t ws_size,
                              hipStream_t stream)
{
    const float* x   = (const float*)d_in[0];
    const int*   src = (const int*)d_in[1];
    const int*   dst = (const int*)d_in[2];
    // d_in[3] = w: reproduced exactly as 1/max(deg,1) from rowptr (validated r3/r4)
    const float* W1  = (const float*)d_in[4];
    const float* b1  = (const float*)d_in[5];
    const float* g1  = (const float*)d_in[6];
    const float* be1 = (const float*)d_in[7];
    const float* W2  = (const float*)d_in[8];
    const float* b2  = (const float*)d_in[9];
    const float* g2  = (const float*)d_in[10];
    const float* be2 = (const float*)d_in[11];
    const float* W3  = (const float*)d_in[12];
    const float* b3  = (const float*)d_in[13];
    const float* zsam = (const float*)d_in[14];
    float* outp = (float*)d_out;

    // ---- workspace layout (~168 MB). A-tensors padded by 128 rows so GEMM
    //      loads/stages are unconditional (pad rows read, never stored). ----
    const int NPAD = NODES + 128;
    uint8_t* base = (uint8_t*)d_ws;
    float* s_scale1 = (float*)(base);
    float* s_shift1 = s_scale1 + 256;
    float* s_scale2 = s_shift1 + 256;
    float* s_shift2 = s_scale2 + 256;
    float* s_sum    = s_shift2 + 256;
    float* s_sq     = s_sum + 256;
    int*   flag     = (int*)(s_sq + 256);

    unsigned short* Wt1 = (unsigned short*)(base + (1 << 14));            // 64 KB
    unsigned short* Wt2 = Wt1 + (size_t)FEAT * HID;                       // 128 KB
    unsigned short* Wt3 = Wt2 + (size_t)HID * HID;                        // 32 KB
    unsigned short* h1  = Wt3 + (size_t)HID * CLS;                        // 51.3 MB (padded)
    unsigned short* h2  = h1 + (size_t)NPAD * HID;                        // 51.3 MB (padded)
    float* logits = (float*)(h2 + (size_t)NPAD * HID);                    // 25.6 MB
    unsigned short* zA  = (unsigned short*)(logits + (size_t)NODES * CLS);// 12.8 MB
    unsigned short* zB  = zA + (size_t)NODES * CLS;                       // 12.8 MB
    int* esrc   = (int*)(zB + (size_t)NODES * CLS);                       // 6.4 MB
    int* cntx   = esrc + EDGES;                                           // 8 x NODES
    int* curx   = cntx + (size_t)8 * NODES;                               // 8 x NODES
    int* rowptr = curx + (size_t)8 * NODES;                               // NODES+1
    int* cnt    = rowptr + (NODES + 1);                                   // NODES
    int* bsum   = cnt + NODES;
    int* boffs  = bsum + 512;
    // pos[] (6.4 MB) aliases h1 (CSR done before GEMM1 writes h1).
    // xb[] (25.7 MB bf16 x, padded) aliases h2 (dead before GEMM2 writes h2).
    int* pos = (int*)h1;
    unsigned short* xb = h2;

    const int NCHUNK2 = (NODES + 63) / 64;      // 1563 (layer 2, 64-row chunks)
    const int NB2     = 256;                    // layer-2 blk0 count (~6 chunks each)
    const int NCHUNK3 = (NODES + 127) / 128;    // 782 (layer 3, 128-row chunks)
    const int NBLK3   = (NCHUNK3 + 1) / 2;      // 391
    const int NCH1    = (NODES + 31) / 32;      // 3125 (layer 1, 32-row chunks)
    const int NB1     = 512;                    // layer-1 blocks
    const int SCANB   = (NODES + 255) / 256;    // 391
    const int EB4     = (EDGES / 4 + 255) / 256;// 1563

    // ---- pack weights (transposed bf16) + x->bf16; zero A-tensor pad rows ----
    packwt_k<<<(FEAT * HID + 255) / 256, 256, 0, stream>>>(W1, Wt1, FEAT, HID);
    packwt_k<<<(HID * HID + 255) / 256, 256, 0, stream>>>(W2, Wt2, HID, HID);
    packwt_k<<<(HID * CLS + 255) / 256, 256, 0, stream>>>(W3, Wt3, HID, CLS);
    xcvt_k<<<(NODES * FEAT / 8 + 255) / 256, 256, 0, stream>>>(x, xb);
    hipMemsetAsync(h1 + (size_t)NODES * HID, 0, 128 * HID * sizeof(unsigned short), stream);
    hipMemsetAsync(xb + (size_t)NODES * FEAT, 0, 128 * FEAT * sizeof(unsigned short), stream);

    // ---- CSR build ----
    hipMemsetAsync(cntx, 0, (size_t)8 * NODES * sizeof(int), stream);
    count_k<<<EB4, 256, 0, stream>>>(dst, cntx);
    sumoff_k<<<SCANB, 256, 0, stream>>>(cntx, cnt);
    scan1_k<<<SCANB, 256, 0, stream>>>(cnt, rowptr, bsum);
    scan2_k<<<1, 512, 0, stream>>>(bsum, boffs, SCANB);
    scan3_k<<<SCANB, 256, 0, stream>>>(rowptr, boffs, cntx, curx);
    posfill_k<<<EB4, 256, 0, stream>>>(dst, curx, pos);
    scat_k<<<EDGES / 256, 256, 0, stream>>>(src, pos, esrc);

    // ---- Layer 1 (col-split, x read once): h1 = xb @ W1 + b1 ----
    hipMemsetAsync(s_sum, 0, 512 * sizeof(float), stream);
    gemm1_k<<<NB1, 256, 0, stream>>>(xb, Wt1, b1, h1, s_sum, s_sq, NODES, NCH1, NB1);
    bnfin_k<<<1, 256, 0, stream>>>(s_sum, s_sq, g1, be1, s_scale1, s_shift1);

    // ---- Layer 2: h2 = relu(bn(h1)) @ W2 + b2 (async-LDS-staged GEMM) ----
    hipMemsetAsync(s_sum, 0, 512 * sizeof(float), stream);
    gemm2_k<<<NB2 * 2, 512, 0, stream>>>(
        h1, Wt2, b2, s_scale1, s_shift1, h2, s_sum, s_sq, NODES, NCHUNK2, NB2);
    bnfin_k<<<1, 256, 0, stream>>>(s_sum, s_sq, g2, be2, s_scale2, s_shift2);
    hipMemsetAsync(h2 + (size_t)NODES * HID, 0, 128 * HID * sizeof(unsigned short), stream);

    // ---- Layer 3: logits fp32, N=64 ----
    gemm_lds_k<true, false, true, HID, 1, 64><<<NBLK3, 256, 0, stream>>>(
        h2, Wt3, b3, s_scale2, s_shift2, logits, nullptr, nullptr, NODES, CLS, NCHUNK3, NBLK3);

    // ---- warm-start blend into zA ----
    hipMemsetAsync(flag, 0, sizeof(int), stream);
    flag_k<<<(NODES * CLS + 255) / 256, 256, 0, stream>>>(zsam, flag);
    blend_k<<<(NODES * CLS + 255) / 256, 256, 0, stream>>>(zsam, logits, flag, zA);

    // ---- K=10 propagation steps, ping-pong zA <-> zB ----
    const int PROPB = (NODES + 31) / 32;
    for (int it = 0; it < KPROP; ++it) {
        const unsigned long long* zi = (const unsigned long long*)((it & 1) ? zB : zA);
        uint4* zo = (uint4*)((it & 1) ? zA : zB);
        prop_k<<<PROPB, 256, 0, stream>>>(rowptr, esrc, zi, logits, zo);
    }
    // KPROP even -> final in zA

    // ---- log_softmax -> d_out ----
    logsoftmax_k<<<(NODES + 3) / 4, 256, 0, stream>>>(zA, outp);
}